// Round 2
// baseline (232.606 us; speedup 1.0000x reference)
//
#include <hip/hip_runtime.h>

typedef unsigned short u16;
typedef float f32x4 __attribute__((ext_vector_type(4)));
typedef __bf16 bf16x8 __attribute__((ext_vector_type(8)));
typedef unsigned short u16x8 __attribute__((ext_vector_type(8)));

// f32 -> bf16 round-to-nearest-even
__device__ __forceinline__ u16 f2bf(float f) {
  unsigned u = __float_as_uint(f);
  unsigned r = u + 0x7fffu + ((u >> 16) & 1u);
  return (u16)(r >> 16);
}

// ---------------------------------------------------------------------------
// proj_q: Qb[b][t][c8] (bf16), t in 0..16383.  grid (256,2), block 256
// ---------------------------------------------------------------------------
__global__ void proj_q_kernel(const float* __restrict__ x, const float* __restrict__ Wq,
                              const float* __restrict__ bq, u16* __restrict__ Qb) {
  __shared__ float xl[256][64];   // x tile [c][t]
  __shared__ float wl[32 * 256];  // Wq
  const int tid = threadIdx.x;
  const int t0 = blockIdx.x * 64, b = blockIdx.y;
  for (int i = tid; i < 4096; i += 256) {
    int c = i >> 4, j = i & 15;
    float4 v = *reinterpret_cast<const float4*>(x + ((size_t)(b * 256 + c)) * 16384 + t0 + j * 4);
    *reinterpret_cast<float4*>(&xl[c][j * 4]) = v;
  }
  for (int i = tid; i < 2048; i += 256)
    *reinterpret_cast<float4*>(&wl[i * 4]) = *reinterpret_cast<const float4*>(Wq + i * 4);
  __syncthreads();
  const int tok = tid & 63, g8 = tid >> 6;  // 4 groups x 8 c8
  float acc[8];
#pragma unroll
  for (int j = 0; j < 8; ++j) acc[j] = bq[g8 * 8 + j];
  for (int c = 0; c < 256; ++c) {
    float xv = xl[c][tok];
#pragma unroll
    for (int j = 0; j < 8; ++j) acc[j] += xv * wl[(g8 * 8 + j) * 256 + c];
  }
  u16x8 o;
#pragma unroll
  for (int j = 0; j < 8; ++j) o[j] = f2bf(acc[j]);
  *reinterpret_cast<u16x8*>(Qb + ((size_t)(b * 16384 + t0 + tok)) * 32 + g8 * 8) = o;
}

// ---------------------------------------------------------------------------
// proj_k: Kt[b][s][c8] (bf16), s in 0..4095 (pooled 64x64). grid (64,2), block 256
// ---------------------------------------------------------------------------
__global__ void proj_k_kernel(const float* __restrict__ x, const float* __restrict__ Wk,
                              const float* __restrict__ bk, u16* __restrict__ Kt) {
  __shared__ float xl[256][64];
  __shared__ float wl[32 * 256];
  const int tid = threadIdx.x;
  const int sy = blockIdx.x, b = blockIdx.y;
  for (int i = tid; i < 8192; i += 256) {
    int c = i >> 5, jj = i & 31;
    size_t base = ((size_t)(b * 256 + c)) * 16384 + (size_t)sy * 256;
    float4 r0 = *reinterpret_cast<const float4*>(x + base + jj * 4);
    float4 r1 = *reinterpret_cast<const float4*>(x + base + 128 + jj * 4);
    xl[c][jj * 2] = (r0.x + r0.y + r1.x + r1.y) * 0.25f;
    xl[c][jj * 2 + 1] = (r0.z + r0.w + r1.z + r1.w) * 0.25f;
  }
  for (int i = tid; i < 2048; i += 256)
    *reinterpret_cast<float4*>(&wl[i * 4]) = *reinterpret_cast<const float4*>(Wk + i * 4);
  __syncthreads();
  const int sx = tid & 63, g8 = tid >> 6;
  float acc[8];
#pragma unroll
  for (int j = 0; j < 8; ++j) acc[j] = bk[g8 * 8 + j];
  for (int c = 0; c < 256; ++c) {
    float xv = xl[c][sx];
#pragma unroll
    for (int j = 0; j < 8; ++j) acc[j] += xv * wl[(g8 * 8 + j) * 256 + c];
  }
  u16x8 o;
#pragma unroll
  for (int j = 0; j < 8; ++j) o[j] = f2bf(acc[j]);
  *reinterpret_cast<u16x8*>(Kt + ((size_t)(b * 4096 + sy * 64 + sx)) * 32 + g8 * 8) = o;
}

// ---------------------------------------------------------------------------
// proj_v: Vb[b][c][s] (bf16). grid (64,2,2), block 256.
// ---------------------------------------------------------------------------
__global__ void proj_v_kernel(const float* __restrict__ x, const float* __restrict__ Wv,
                              const float* __restrict__ bvp, u16* __restrict__ Vb) {
  __shared__ float xl[256][64];
  __shared__ float wvl[32 * 256];
  const int tid = threadIdx.x;
  const int sy = blockIdx.x, b = blockIdx.y, z = blockIdx.z;
  for (int i = tid; i < 8192; i += 256) {
    int c = i >> 5, jj = i & 31;
    size_t base = ((size_t)(b * 256 + c)) * 16384 + (size_t)sy * 256;
    float4 r0 = *reinterpret_cast<const float4*>(x + base + jj * 4);
    float4 r1 = *reinterpret_cast<const float4*>(x + base + 128 + jj * 4);
    xl[c][jj * 2] = (r0.x + r0.y + r1.x + r1.y) * 0.25f;
    xl[c][jj * 2 + 1] = (r0.z + r0.w + r1.z + r1.w) * 0.25f;
  }
  const int s = tid & 63, grp = tid >> 6;
  for (int p = 0; p < 4; ++p) {
    int oc = z * 4 + p;
    __syncthreads();
    for (int i = tid; i < 2048; i += 256)
      *reinterpret_cast<float4*>(&wvl[i * 4]) =
          *reinterpret_cast<const float4*>(Wv + (size_t)oc * 8192 + i * 4);
    __syncthreads();
    int cb = oc * 32 + grp * 8;
    float acc[8];
#pragma unroll
    for (int j = 0; j < 8; ++j) acc[j] = bvp[cb + j];
    for (int c = 0; c < 256; ++c) {
      float xv = xl[c][s];
#pragma unroll
      for (int j = 0; j < 8; ++j) acc[j] += xv * wvl[(grp * 8 + j) * 256 + c];
    }
#pragma unroll
    for (int j = 0; j < 8; ++j)
      Vb[((size_t)(b * 256 + cb + j)) * 4096 + sy * 64 + s] = f2bf(acc[j]);
  }
}

// ---------------------------------------------------------------------------
// attn v2: no K/Q/V LDS staging — Q fragments hoisted to registers (loop
// invariant), K/V MFMA fragments read directly from global (L2-resident,
// FETCH_SIZE round-1 proved re-reads are cache-absorbed). Next-iter K/V
// fragment loads issued right after current ones are consumed -> latency
// overlaps compute. Only P round-trips through LDS (transpose for PV).
// 2 barriers/iter (was 3). LDS 9KB (was 50KB).
// grid (256, 2), block 256 (4 waves). Wave w: QK keys [16w,16w+16),
// PV channels [64w, 64w+64).
// ---------------------------------------------------------------------------
__global__ __launch_bounds__(256, 2) void attn_kernel(
    const u16* __restrict__ Qb, const u16* __restrict__ Kt, const u16* __restrict__ Vb,
    const float* __restrict__ x, const float* __restrict__ gamma, float* __restrict__ out) {
  __shared__ __align__(16) u16 p_lds[64 * 64];  // [tok][key-chunk swizzled]  8KB
  __shared__ float lred[4][64];

  const int tid = threadIdx.x;
  const int lane = tid & 63, w = tid >> 6;
  const int l15 = lane & 15, l4 = lane >> 4;
  const int t0 = blockIdx.x * 64, b = blockIdx.y;

  const u16* Qp = Qb + (size_t)(b * 16384 + t0) * 32;
  const u16* Kp = Kt + (size_t)b * 4096 * 32;
  const u16* Vp = Vb + (size_t)b * 256 * 4096;

  // Q fragments: loop-invariant, load once. A-frag row = mt*16+l15, k-chunk l4.
  bf16x8 qfr[4];
#pragma unroll
  for (int mt = 0; mt < 4; ++mt)
    qfr[mt] = *reinterpret_cast<const bf16x8*>(Qp + (size_t)(mt * 16 + l15) * 32 + l4 * 8);

  const int key = w * 16 + l15;  // this wave's QK key column
  // prologue: fragments for kt=0 in flight
  bf16x8 kfr = *reinterpret_cast<const bf16x8*>(Kp + (size_t)key * 32 + l4 * 8);
  bf16x8 vfr[2][4];
#pragma unroll
  for (int ks = 0; ks < 2; ++ks)
#pragma unroll
    for (int nt = 0; nt < 4; ++nt) {
      int ch = w * 64 + nt * 16 + l15;
      vfr[ks][nt] =
          *reinterpret_cast<const bf16x8*>(Vp + (size_t)ch * 4096 + ks * 32 + l4 * 8);
    }

  f32x4 acc[4][4] = {};  // [tok-tile][ch-tile]
  float lsum[16] = {};
  const float SCALE = 0.17677669529663687f;  // 1/sqrt(32)
  const f32x4 zero = {0.0f, 0.0f, 0.0f, 0.0f};

  for (int kt = 0; kt < 64; ++kt) {
    const int ktn = kt < 63 ? kt + 1 : 63;  // clamp: avoid OOB prefetch on last iter

    // ---- QK: S[tok][key] for this wave's 16 keys ----
    f32x4 sfr[4];
#pragma unroll
    for (int mt = 0; mt < 4; ++mt)
      sfr[mt] = __builtin_amdgcn_mfma_f32_16x16x32_bf16(qfr[mt], kfr, zero, 0, 0, 0);
    // prefetch next K fragment (kfr consumed above)
    kfr = *reinterpret_cast<const bf16x8*>(Kp + (size_t)(ktn * 64 + key) * 32 + l4 * 8);

    // exp + row-sum partials + write P (swizzled [tok][key] for PV A-operand)
#pragma unroll
    for (int mt = 0; mt < 4; ++mt) {
#pragma unroll
      for (int r = 0; r < 4; ++r) {
        float p = __expf(sfr[mt][r] * SCALE);
        lsum[mt * 4 + r] += p;
        int tok = mt * 16 + l4 * 4 + r;  // C-layout row
        p_lds[tok * 64 + (((key >> 3) ^ (tok & 7)) * 8) + (key & 7)] = f2bf(p);
      }
    }
    __syncthreads();  // P tile ready

    // ---- PV: acc[tok][ch] += P * V^T, channels 64w..64w+63 ----
#pragma unroll
    for (int ks = 0; ks < 2; ++ks) {
      bf16x8 afr[4];
#pragma unroll
      for (int mt = 0; mt < 4; ++mt) {
        int tok = mt * 16 + l15;
        afr[mt] =
            *reinterpret_cast<const bf16x8*>(p_lds + (tok * 8 + ((ks * 4 + l4) ^ (tok & 7))) * 8);
      }
#pragma unroll
      for (int mt = 0; mt < 4; ++mt)
#pragma unroll
        for (int nt = 0; nt < 4; ++nt)
          acc[mt][nt] =
              __builtin_amdgcn_mfma_f32_16x16x32_bf16(afr[mt], vfr[ks][nt], acc[mt][nt], 0, 0, 0);
    }
    // prefetch next V fragments (vfr consumed above); in flight across barrier
#pragma unroll
    for (int ks = 0; ks < 2; ++ks)
#pragma unroll
      for (int nt = 0; nt < 4; ++nt) {
        int ch = w * 64 + nt * 16 + l15;
        vfr[ks][nt] = *reinterpret_cast<const bf16x8*>(Vp + (size_t)ch * 4096 + ktn * 64 +
                                                       ks * 32 + l4 * 8);
      }
    __syncthreads();  // P reads done before next iter's writes
  }

  // ---- finish row sums: reduce over the 16 key-column lanes, then waves ----
#pragma unroll
  for (int d = 1; d < 16; d <<= 1)
#pragma unroll
    for (int i = 0; i < 16; ++i) lsum[i] += __shfl_xor(lsum[i], d, 64);
  if (l15 == 0) {
#pragma unroll
    for (int mt = 0; mt < 4; ++mt)
#pragma unroll
      for (int r = 0; r < 4; ++r) lred[w][mt * 16 + l4 * 4 + r] = lsum[mt * 4 + r];
  }
  __syncthreads();

  const float g = gamma[0];
  float linv[16];
#pragma unroll
  for (int mt = 0; mt < 4; ++mt)
#pragma unroll
    for (int r = 0; r < 4; ++r) {
      int tok = mt * 16 + l4 * 4 + r;
      linv[mt * 4 + r] = 1.0f / (lred[0][tok] + lred[1][tok] + lred[2][tok] + lred[3][tok]);
    }
  // ---- epilogue: out = gamma * acc / l + x ; float4 along tokens ----
#pragma unroll
  for (int mt = 0; mt < 4; ++mt) {
#pragma unroll
    for (int nt = 0; nt < 4; ++nt) {
      int ch = w * 64 + nt * 16 + l15;
      size_t idx = ((size_t)(b * 256 + ch)) * 16384 + t0 + mt * 16 + l4 * 4;
      float4 xr = *reinterpret_cast<const float4*>(x + idx);
      float4 o;
      o.x = g * acc[mt][nt][0] * linv[mt * 4 + 0] + xr.x;
      o.y = g * acc[mt][nt][1] * linv[mt * 4 + 1] + xr.y;
      o.z = g * acc[mt][nt][2] * linv[mt * 4 + 2] + xr.z;
      o.w = g * acc[mt][nt][3] * linv[mt * 4 + 3] + xr.w;
      *reinterpret_cast<float4*>(out + idx) = o;
    }
  }
}

// ---------------------------------------------------------------------------
extern "C" void kernel_launch(void* const* d_in, const int* in_sizes, int n_in,
                              void* d_out, int out_size, void* d_ws, size_t ws_size,
                              hipStream_t stream) {
  const float* x = (const float*)d_in[0];
  const float* Wq = (const float*)d_in[1];
  const float* bq = (const float*)d_in[2];
  const float* Wk = (const float*)d_in[3];
  const float* bk = (const float*)d_in[4];
  const float* Wv = (const float*)d_in[5];
  const float* bv = (const float*)d_in[6];
  const float* gamma = (const float*)d_in[7];
  float* out = (float*)d_out;

  char* ws = (char*)d_ws;
  u16* Qb = (u16*)ws;                                // 2 MB  : [2][16384][32]
  u16* Kt = (u16*)(ws + (2u << 20));                 // 512 KB: [2][4096][32]
  u16* Vb = (u16*)(ws + (2u << 20) + (512u << 10));  // 4 MB  : [2][256][4096]

  proj_q_kernel<<<dim3(256, 2), 256, 0, stream>>>(x, Wq, bq, Qb);
  proj_k_kernel<<<dim3(64, 2), 256, 0, stream>>>(x, Wk, bk, Kt);
  proj_v_kernel<<<dim3(64, 2, 2), 256, 0, stream>>>(x, Wv, bv, Vb);
  attn_kernel<<<dim3(256, 2), 256, 0, stream>>>(Qb, Kt, Vb, x, gamma, out);
}

// Round 3
// 220.243 us; speedup vs baseline: 1.0561x; 1.0561x over previous
//
#include <hip/hip_runtime.h>

typedef unsigned short u16;
typedef unsigned int u32;
typedef float f32x4 __attribute__((ext_vector_type(4)));
typedef __bf16 bf16x8 __attribute__((ext_vector_type(8)));
typedef unsigned short u16x8 __attribute__((ext_vector_type(8)));

// f32 -> bf16 round-to-nearest-even (scalar)
__device__ __forceinline__ u16 f2bf(float f) {
  unsigned u = __float_as_uint(f);
  unsigned r = u + 0x7fffu + ((u >> 16) & 1u);
  return (u16)(r >> 16);
}
// packed f32 pair -> 2x bf16 in one u32 (lo = first arg)
__device__ __forceinline__ u32 cvt_pk_bf16(float lo, float hi) {
  u32 r;
  asm("v_cvt_pk_bf16_f32 %0, %1, %2" : "=v"(r) : "v"(lo), "v"(hi));
  return r;
}
// hardware 2^x
__device__ __forceinline__ float exp2_hw(float x) {
  float r;
  asm("v_exp_f32 %0, %1" : "=v"(r) : "v"(x));
  return r;
}
__device__ __forceinline__ bf16x8 f32x8_to_bf16x8(float4 a, float4 b) {
  union { u32 u[4]; bf16x8 v; } t;
  t.u[0] = cvt_pk_bf16(a.x, a.y);
  t.u[1] = cvt_pk_bf16(a.z, a.w);
  t.u[2] = cvt_pk_bf16(b.x, b.y);
  t.u[3] = cvt_pk_bf16(b.z, b.w);
  return t.v;
}

// 1/sqrt(32) * log2(e)  — softmax scale folded with exp->exp2 conversion
#define QSCALE 0.25513936f

// ---------------------------------------------------------------------------
// proj_kernel: blocks 0..511 -> Q path (64 tokens each, MFMA from LDS x^T and
// scale-folded Wq). blocks 512..639 -> fused pooled K+V path (64 pooled s
// each; W fragments read f32 from global + cvt_pk).
// Layouts (same as round 2): Qb[b][t][32], Kt[b][s][32], Vb[b][ch][4096].
// ---------------------------------------------------------------------------
__global__ __launch_bounds__(256) void proj_kernel(
    const float* __restrict__ x, const float* __restrict__ Wq, const float* __restrict__ bq,
    const float* __restrict__ Wk, const float* __restrict__ bk, const float* __restrict__ Wv,
    const float* __restrict__ bv, u16* __restrict__ Qb, u16* __restrict__ Kt,
    u16* __restrict__ Vb) {
  __shared__ __align__(16) u16 smem[24576];  // 48KB: xt(32KB) + wq(16KB) | xs(32KB)
  const int tid = threadIdx.x;
  const int lane = tid & 63, w = tid >> 6;
  const int l15 = lane & 15, l4 = lane >> 4;
  const int bi = blockIdx.x;
  const f32x4 zero = {0.f, 0.f, 0.f, 0.f};

  if (bi < 512) {
    // ================= Q path =================
    u16* xt = smem;            // [64 t][256 c] bf16, swizzled
    u16* wq = smem + 16384;    // [32 oc][256 c] bf16, swizzled, pre-scaled
    const int b = bi >> 8, tb = bi & 255;
    const float* xp = x + (size_t)b * 256 * 16384 + tb * 64;

    // stage Wq (scale folded)
    for (int i = tid; i < 4096; i += 256) {
      int oc = i >> 7, c0 = (i & 127) * 2;
      float2 f = *reinterpret_cast<const float2*>(Wq + oc * 256 + c0);
      u32 pk = cvt_pk_bf16(f.x * QSCALE, f.y * QSCALE);
      *reinterpret_cast<u32*>((char*)wq + oc * 512 + (((c0 >> 3) ^ (oc & 7)) * 16) +
                              (c0 & 7) * 2) = pk;
    }
    // stage x tile transposed: xt[t][c]
#pragma unroll
    for (int rr = 0; rr < 4; ++rr) {
      int c = rr * 64 + (tid >> 2);
      int tch = (tid & 3) * 16;
      const float* src = xp + (size_t)c * 16384 + tch;
      int cb = ((c >> 3) & 7) * 0;  // (placeholder, swizzle computed per write)
      (void)cb;
#pragma unroll
      for (int u = 0; u < 4; ++u) {
        float4 f = *reinterpret_cast<const float4*>(src + u * 4);
        int t = tch + u * 4;
        *reinterpret_cast<u16*>((char*)xt + (t + 0) * 512 + (((c >> 3) ^ ((t + 0) & 7)) * 16) + (c & 7) * 2) = f2bf(f.x);
        *reinterpret_cast<u16*>((char*)xt + (t + 1) * 512 + (((c >> 3) ^ ((t + 1) & 7)) * 16) + (c & 7) * 2) = f2bf(f.y);
        *reinterpret_cast<u16*>((char*)xt + (t + 2) * 512 + (((c >> 3) ^ ((t + 2) & 7)) * 16) + (c & 7) * 2) = f2bf(f.z);
        *reinterpret_cast<u16*>((char*)xt + (t + 3) * 512 + (((c >> 3) ^ ((t + 3) & 7)) * 16) + (c & 7) * 2) = f2bf(f.w);
      }
    }
    __syncthreads();

    // GEMM: wave w owns n-tile (16 toks), m = 2 tiles (32 oc), k = 8 steps
    f32x4 acc[2] = {zero, zero};
    const int tl = w * 16 + l15;  // local token (B col)
#pragma unroll
    for (int k = 0; k < 8; ++k) {
      bf16x8 bf = *reinterpret_cast<const bf16x8*>((char*)xt + tl * 512 +
                                                   (((k * 4 + l4) ^ (tl & 7)) * 16));
#pragma unroll
      for (int m = 0; m < 2; ++m) {
        int oc = m * 16 + l15;
        bf16x8 af = *reinterpret_cast<const bf16x8*>((char*)wq + oc * 512 +
                                                     (((k * 4 + l4) ^ (oc & 7)) * 16));
        acc[m] = __builtin_amdgcn_mfma_f32_16x16x32_bf16(af, bf, acc[m], 0, 0, 0);
      }
    }
    // bias (scale-folded) + packed store: Qb[b][t][oc]
    const int t = tb * 64 + tl;
#pragma unroll
    for (int m = 0; m < 2; ++m) {
      int oc0 = m * 16 + l4 * 4;
      u32 p0 = cvt_pk_bf16(acc[m][0] + bq[oc0] * QSCALE, acc[m][1] + bq[oc0 + 1] * QSCALE);
      u32 p1 = cvt_pk_bf16(acc[m][2] + bq[oc0 + 2] * QSCALE, acc[m][3] + bq[oc0 + 3] * QSCALE);
      u16* dst = Qb + ((size_t)b * 16384 + t) * 32 + oc0;
      *reinterpret_cast<u32*>(dst) = p0;
      *reinterpret_cast<u32*>(dst + 2) = p1;
    }
  } else {
    // ================= fused K+V path =================
    u16* xs = smem;  // pooled [64 s][256 c] bf16, swizzled
    const int j = bi - 512;
    const int b = j >> 6, sy = j & 63;
    const float* xb = x + (size_t)b * 256 * 16384;

    // pooled stage: xs[s][c] = mean2x2
#pragma unroll
    for (int rr = 0; rr < 4; ++rr) {
      int c = rr * 64 + (tid >> 2);
      int f4base = (tid & 3) * 8;
      const float* r0 = xb + (size_t)c * 16384 + (size_t)sy * 256;
#pragma unroll
      for (int u = 0; u < 8; ++u) {
        int jj = f4base + u;
        float4 a = *reinterpret_cast<const float4*>(r0 + jj * 4);
        float4 d = *reinterpret_cast<const float4*>(r0 + 128 + jj * 4);
        float p0 = (a.x + a.y + d.x + d.y) * 0.25f;
        float p1 = (a.z + a.w + d.z + d.w) * 0.25f;
        int s0 = jj * 2;
        *reinterpret_cast<u16*>((char*)xs + (s0 + 0) * 512 + (((c >> 3) ^ ((s0 + 0) & 7)) * 16) + (c & 7) * 2) = f2bf(p0);
        *reinterpret_cast<u16*>((char*)xs + (s0 + 1) * 512 + (((c >> 3) ^ ((s0 + 1) & 7)) * 16) + (c & 7) * 2) = f2bf(p1);
      }
    }
    __syncthreads();

    // GEMM: wave w = n-tile (16 s). m-tiles: 0..1 = K (32 oc), 2..17 = V (256 oc)
    f32x4 acc[18];
#pragma unroll
    for (int m = 0; m < 18; ++m) acc[m] = zero;
    const int sl = w * 16 + l15;  // local s (B col)
#pragma unroll
    for (int k = 0; k < 8; ++k) {
      bf16x8 bf = *reinterpret_cast<const bf16x8*>((char*)xs + sl * 512 +
                                                   (((k * 4 + l4) ^ (sl & 7)) * 16));
#pragma unroll
      for (int m = 0; m < 2; ++m) {
        const float* wr = Wk + (size_t)(m * 16 + l15) * 256 + k * 32 + l4 * 8;
        float4 fa = *reinterpret_cast<const float4*>(wr);
        float4 fb = *reinterpret_cast<const float4*>(wr + 4);
        acc[m] = __builtin_amdgcn_mfma_f32_16x16x32_bf16(f32x8_to_bf16x8(fa, fb), bf, acc[m], 0, 0, 0);
      }
#pragma unroll
      for (int m = 0; m < 16; ++m) {
        const float* wr = Wv + (size_t)(m * 16 + l15) * 256 + k * 32 + l4 * 8;
        float4 fa = *reinterpret_cast<const float4*>(wr);
        float4 fb = *reinterpret_cast<const float4*>(wr + 4);
        acc[2 + m] = __builtin_amdgcn_mfma_f32_16x16x32_bf16(f32x8_to_bf16x8(fa, fb), bf, acc[2 + m], 0, 0, 0);
      }
    }
    // K store (packed): Kt[b][s][oc]
#pragma unroll
    for (int m = 0; m < 2; ++m) {
      int oc0 = m * 16 + l4 * 4;
      u32 p0 = cvt_pk_bf16(acc[m][0] + bk[oc0], acc[m][1] + bk[oc0 + 1]);
      u32 p1 = cvt_pk_bf16(acc[m][2] + bk[oc0 + 2], acc[m][3] + bk[oc0 + 3]);
      u16* dst = Kt + ((size_t)b * 4096 + sy * 64 + sl) * 32 + oc0;
      *reinterpret_cast<u32*>(dst) = p0;
      *reinterpret_cast<u32*>(dst + 2) = p1;
    }
    // V store: Vb[b][oc][s]
#pragma unroll
    for (int m = 0; m < 16; ++m) {
#pragma unroll
      for (int r = 0; r < 4; ++r) {
        int oc = m * 16 + l4 * 4 + r;
        Vb[((size_t)b * 256 + oc) * 4096 + sy * 64 + sl] = f2bf(acc[2 + m][r] + bv[oc]);
      }
    }
  }
}

// ---------------------------------------------------------------------------
// attn v3: swapped QK (S^T = mfma(K,Q)) so each lane holds 4 consecutive keys
// -> cvt_pk packed b32 P-writes, lsum[4]. Double-buffered p_lds, ONE barrier
// per iter: PV(kt) || QK(kt+1)+exp+write P[kt+1]. K/V frags direct from L2
// with register prefetch. Scale+log2e pre-folded into Q -> exp = v_exp_f32.
// XCD swizzle: XCDs 0-3 batch 0, 4-7 batch 1, contiguous token quarters.
// ---------------------------------------------------------------------------
__global__ __launch_bounds__(256, 2) void attn_kernel(
    const u16* __restrict__ Qb, const u16* __restrict__ Kt, const u16* __restrict__ Vb,
    const float* __restrict__ x, const float* __restrict__ gamma, float* __restrict__ out) {
  __shared__ __align__(16) u16 p_lds[2][64 * 64];  // 16KB
  __shared__ float lred[4][64];

  const int tid = threadIdx.x;
  const int lane = tid & 63, w = tid >> 6;
  const int l15 = lane & 15, l4 = lane >> 4;
  const int raw = blockIdx.x;
  const int xcd = raw & 7, loc = raw >> 3;
  const int b = xcd >> 2;
  const int t0 = ((xcd & 3) * 64 + loc) * 64;

  const u16* Qp = Qb + (size_t)(b * 16384 + t0) * 32;
  const u16* Kp = Kt + (size_t)b * 4096 * 32;
  const u16* Vp = Vb + (size_t)b * 256 * 4096;

  // Q fragments (loop-invariant): B-operand col = tok = mt*16+l15, k-chunk l4
  bf16x8 qfr[4];
#pragma unroll
  for (int mt = 0; mt < 4; ++mt)
    qfr[mt] = *reinterpret_cast<const bf16x8*>(Qp + (size_t)(mt * 16 + l15) * 32 + l4 * 8);

  const int key = w * 16 + l15;       // A-operand row for QK
  const int key0 = w * 16 + l4 * 4;   // this lane's first S^T key (C rows)
  // P write address pieces: byte = tok*128 + ((key0>>3)^(tok&7))*16 + (key0&7)*2
  const int pw_chunk = w * 2 + (l4 >> 1), pw_off = (l4 & 1) * 8;

  bf16x8 kfr = *reinterpret_cast<const bf16x8*>(Kp + (size_t)key * 32 + l4 * 8);
  bf16x8 vfr[2][4];
#pragma unroll
  for (int ks = 0; ks < 2; ++ks)
#pragma unroll
    for (int nt = 0; nt < 4; ++nt) {
      int ch = w * 64 + nt * 16 + l15;
      vfr[ks][nt] = *reinterpret_cast<const bf16x8*>(Vp + (size_t)ch * 4096 + ks * 32 + l4 * 8);
    }

  f32x4 acc[4][4] = {};
  float lsum[4] = {};
  const f32x4 zero = {0.f, 0.f, 0.f, 0.f};

  // ---- prologue: QK(0) + exp + write p[0] ----
  {
    f32x4 sfr[4];
#pragma unroll
    for (int mt = 0; mt < 4; ++mt)
      sfr[mt] = __builtin_amdgcn_mfma_f32_16x16x32_bf16(kfr, qfr[mt], zero, 0, 0, 0);
    kfr = *reinterpret_cast<const bf16x8*>(Kp + (size_t)(64 + key) * 32 + l4 * 8);  // K(1)
#pragma unroll
    for (int mt = 0; mt < 4; ++mt) {
      float p0 = exp2_hw(sfr[mt][0]), p1 = exp2_hw(sfr[mt][1]);
      float p2 = exp2_hw(sfr[mt][2]), p3 = exp2_hw(sfr[mt][3]);
      lsum[mt] += (p0 + p1) + (p2 + p3);
      int tok = mt * 16 + l15;
      char* base = (char*)p_lds + tok * 128 + ((pw_chunk ^ (tok & 7)) * 16) + pw_off;
      *reinterpret_cast<u32*>(base) = cvt_pk_bf16(p0, p1);
      *reinterpret_cast<u32*>(base + 4) = cvt_pk_bf16(p2, p3);
    }
  }
  __syncthreads();

  for (int kt = 0; kt < 64; ++kt) {
    const int cur = kt & 1;
    // ---- PV(kt): acc += P * V^T ----
#pragma unroll
    for (int ks = 0; ks < 2; ++ks) {
      bf16x8 afr[4];
#pragma unroll
      for (int mt = 0; mt < 4; ++mt) {
        int tok = mt * 16 + l15;
        afr[mt] = *reinterpret_cast<const bf16x8*>((char*)p_lds + cur * 8192 + tok * 128 +
                                                   (((ks * 4 + l4) ^ (tok & 7)) * 16));
      }
#pragma unroll
      for (int mt = 0; mt < 4; ++mt)
#pragma unroll
        for (int nt = 0; nt < 4; ++nt)
          acc[mt][nt] =
              __builtin_amdgcn_mfma_f32_16x16x32_bf16(afr[mt], vfr[ks][nt], acc[mt][nt], 0, 0, 0);
    }
    if (kt < 63) {
      const int ktn = kt + 1;
      // prefetch V(kt+1) (vfr consumed above)
#pragma unroll
      for (int ks = 0; ks < 2; ++ks)
#pragma unroll
        for (int nt = 0; nt < 4; ++nt) {
          int ch = w * 64 + nt * 16 + l15;
          vfr[ks][nt] = *reinterpret_cast<const bf16x8*>(Vp + (size_t)ch * 4096 + ktn * 64 +
                                                         ks * 32 + l4 * 8);
        }
      // ---- QK(kt+1) + exp + packed write p[cur^1] ----
      f32x4 sfr[4];
#pragma unroll
      for (int mt = 0; mt < 4; ++mt)
        sfr[mt] = __builtin_amdgcn_mfma_f32_16x16x32_bf16(kfr, qfr[mt], zero, 0, 0, 0);
      const int kt2 = (kt < 62) ? kt + 2 : 63;
      kfr = *reinterpret_cast<const bf16x8*>(Kp + (size_t)(kt2 * 64 + key) * 32 + l4 * 8);
#pragma unroll
      for (int mt = 0; mt < 4; ++mt) {
        float p0 = exp2_hw(sfr[mt][0]), p1 = exp2_hw(sfr[mt][1]);
        float p2 = exp2_hw(sfr[mt][2]), p3 = exp2_hw(sfr[mt][3]);
        lsum[mt] += (p0 + p1) + (p2 + p3);
        int tok = mt * 16 + l15;
        char* base =
            (char*)p_lds + (cur ^ 1) * 8192 + tok * 128 + ((pw_chunk ^ (tok & 7)) * 16) + pw_off;
        *reinterpret_cast<u32*>(base) = cvt_pk_bf16(p0, p1);
        *reinterpret_cast<u32*>(base + 4) = cvt_pk_bf16(p2, p3);
      }
    }
    __syncthreads();
  }

  // ---- row sums: reduce over l4 groups, then waves ----
#pragma unroll
  for (int i = 0; i < 4; ++i) {
    lsum[i] += __shfl_xor(lsum[i], 16, 64);
    lsum[i] += __shfl_xor(lsum[i], 32, 64);
  }
  if (l4 == 0) {
#pragma unroll
    for (int mt = 0; mt < 4; ++mt) lred[w][mt * 16 + l15] = lsum[mt];
  }
  __syncthreads();

  const float g = gamma[0];
  float linv[16];
#pragma unroll
  for (int mt = 0; mt < 4; ++mt)
#pragma unroll
    for (int r = 0; r < 4; ++r) {
      int tok = mt * 16 + l4 * 4 + r;
      linv[mt * 4 + r] = 1.0f / (lred[0][tok] + lred[1][tok] + lred[2][tok] + lred[3][tok]);
    }
  // ---- epilogue: out = gamma * acc / l + x ----
#pragma unroll
  for (int mt = 0; mt < 4; ++mt) {
#pragma unroll
    for (int nt = 0; nt < 4; ++nt) {
      int ch = w * 64 + nt * 16 + l15;
      size_t idx = ((size_t)(b * 256 + ch)) * 16384 + t0 + mt * 16 + l4 * 4;
      float4 xr = *reinterpret_cast<const float4*>(x + idx);
      float4 o;
      o.x = g * acc[mt][nt][0] * linv[mt * 4 + 0] + xr.x;
      o.y = g * acc[mt][nt][1] * linv[mt * 4 + 1] + xr.y;
      o.z = g * acc[mt][nt][2] * linv[mt * 4 + 2] + xr.z;
      o.w = g * acc[mt][nt][3] * linv[mt * 4 + 3] + xr.w;
      *reinterpret_cast<float4*>(out + idx) = o;
    }
  }
}

// ---------------------------------------------------------------------------
extern "C" void kernel_launch(void* const* d_in, const int* in_sizes, int n_in,
                              void* d_out, int out_size, void* d_ws, size_t ws_size,
                              hipStream_t stream) {
  const float* x = (const float*)d_in[0];
  const float* Wq = (const float*)d_in[1];
  const float* bq = (const float*)d_in[2];
  const float* Wk = (const float*)d_in[3];
  const float* bk = (const float*)d_in[4];
  const float* Wv = (const float*)d_in[5];
  const float* bv = (const float*)d_in[6];
  const float* gamma = (const float*)d_in[7];
  float* out = (float*)d_out;

  char* ws = (char*)d_ws;
  u16* Qb = (u16*)ws;                                // 2 MB  : [2][16384][32]
  u16* Kt = (u16*)(ws + (2u << 20));                 // 512 KB: [2][4096][32]
  u16* Vb = (u16*)(ws + (2u << 20) + (512u << 10));  // 4 MB  : [2][256][4096]

  proj_kernel<<<dim3(640), 256, 0, stream>>>(x, Wq, bq, Wk, bk, Wv, bv, Qb, Kt, Vb);
  attn_kernel<<<dim3(512), 256, 0, stream>>>(Qb, Kt, Vb, x, gamma, out);
}

// Round 5
// 207.458 us; speedup vs baseline: 1.1212x; 1.0616x over previous
//
#include <hip/hip_runtime.h>

typedef unsigned short u16;
typedef unsigned int u32;
typedef float f32x4 __attribute__((ext_vector_type(4)));
typedef __bf16 bf16x8 __attribute__((ext_vector_type(8)));
typedef unsigned short u16x8 __attribute__((ext_vector_type(8)));

// f32 -> bf16 round-to-nearest-even (scalar)
__device__ __forceinline__ u16 f2bf(float f) {
  unsigned u = __float_as_uint(f);
  unsigned r = u + 0x7fffu + ((u >> 16) & 1u);
  return (u16)(r >> 16);
}
// packed f32 pair -> 2x bf16 in one u32 (lo = first arg)
__device__ __forceinline__ u32 cvt_pk_bf16(float lo, float hi) {
  u32 r;
  asm("v_cvt_pk_bf16_f32 %0, %1, %2" : "=v"(r) : "v"(lo), "v"(hi));
  return r;
}
// hardware 2^x
__device__ __forceinline__ float exp2_hw(float x) {
  float r;
  asm("v_exp_f32 %0, %1" : "=v"(r) : "v"(x));
  return r;
}
__device__ __forceinline__ bf16x8 f32x8_to_bf16x8(float4 a, float4 b) {
  union { u32 u[4]; bf16x8 v; } t;
  t.u[0] = cvt_pk_bf16(a.x, a.y);
  t.u[1] = cvt_pk_bf16(a.z, a.w);
  t.u[2] = cvt_pk_bf16(b.x, b.y);
  t.u[3] = cvt_pk_bf16(b.z, b.w);
  return t.v;
}

// 1/sqrt(32) * log2(e)  — softmax scale folded with exp->exp2 conversion
#define QSCALE 0.25513936f

// ---------------------------------------------------------------------------
// proj_kernel: blocks 0..127 -> fused pooled K+V path (heavy; scheduled first).
// blocks 128..639 -> Q path, ROUND-3-VERIFIED LDS-staged MFMA (x^T + Wq
// staged swizzled in LDS; QSCALE folded into Wq/bq).
// Layouts: Qb[b][t][32], Kt[b][s][32], Vb[b][ch][4096].
// ---------------------------------------------------------------------------
__global__ __launch_bounds__(256) void proj_kernel(
    const float* __restrict__ x, const float* __restrict__ Wq, const float* __restrict__ bq,
    const float* __restrict__ Wk, const float* __restrict__ bk, const float* __restrict__ Wv,
    const float* __restrict__ bv, u16* __restrict__ Qb, u16* __restrict__ Kt,
    u16* __restrict__ Vb) {
  __shared__ __align__(16) u16 smem[24576];  // 48KB: xt(32KB)+wq(16KB) | xs(32KB)
  const int tid = threadIdx.x;
  const int lane = tid & 63, w = tid >> 6;
  const int l15 = lane & 15, l4 = lane >> 4;
  const int bi = blockIdx.x;
  const f32x4 zero = {0.f, 0.f, 0.f, 0.f};

  if (bi >= 128) {
    // ================= Q path (round-3 verbatim, LDS-staged) =================
    u16* xt = smem;          // [64 t][256 c] bf16, swizzled
    u16* wq = smem + 16384;  // [32 oc][256 c] bf16, swizzled, pre-scaled
    const int j = bi - 128;
    const int b = j >> 8, tb = j & 255;
    const float* xp = x + (size_t)b * 256 * 16384 + tb * 64;

    // stage Wq (scale folded)
    for (int i = tid; i < 4096; i += 256) {
      int oc = i >> 7, c0 = (i & 127) * 2;
      float2 f = *reinterpret_cast<const float2*>(Wq + oc * 256 + c0);
      u32 pk = cvt_pk_bf16(f.x * QSCALE, f.y * QSCALE);
      *reinterpret_cast<u32*>((char*)wq + oc * 512 + (((c0 >> 3) ^ (oc & 7)) * 16) +
                              (c0 & 7) * 2) = pk;
    }
    // stage x tile transposed: xt[t][c]
#pragma unroll
    for (int rr = 0; rr < 4; ++rr) {
      int c = rr * 64 + (tid >> 2);
      int tch = (tid & 3) * 16;
      const float* src = xp + (size_t)c * 16384 + tch;
#pragma unroll
      for (int u = 0; u < 4; ++u) {
        float4 f = *reinterpret_cast<const float4*>(src + u * 4);
        int t = tch + u * 4;
        *reinterpret_cast<u16*>((char*)xt + (t + 0) * 512 + (((c >> 3) ^ ((t + 0) & 7)) * 16) + (c & 7) * 2) = f2bf(f.x);
        *reinterpret_cast<u16*>((char*)xt + (t + 1) * 512 + (((c >> 3) ^ ((t + 1) & 7)) * 16) + (c & 7) * 2) = f2bf(f.y);
        *reinterpret_cast<u16*>((char*)xt + (t + 2) * 512 + (((c >> 3) ^ ((t + 2) & 7)) * 16) + (c & 7) * 2) = f2bf(f.z);
        *reinterpret_cast<u16*>((char*)xt + (t + 3) * 512 + (((c >> 3) ^ ((t + 3) & 7)) * 16) + (c & 7) * 2) = f2bf(f.w);
      }
    }
    __syncthreads();

    // GEMM: wave w owns n-tile (16 toks), m = 2 tiles (32 oc), k = 8 steps
    f32x4 acc[2] = {zero, zero};
    const int tl = w * 16 + l15;  // local token (B col)
#pragma unroll
    for (int k = 0; k < 8; ++k) {
      bf16x8 bf = *reinterpret_cast<const bf16x8*>((char*)xt + tl * 512 +
                                                   (((k * 4 + l4) ^ (tl & 7)) * 16));
#pragma unroll
      for (int m = 0; m < 2; ++m) {
        int oc = m * 16 + l15;
        bf16x8 af = *reinterpret_cast<const bf16x8*>((char*)wq + oc * 512 +
                                                     (((k * 4 + l4) ^ (oc & 7)) * 16));
        acc[m] = __builtin_amdgcn_mfma_f32_16x16x32_bf16(af, bf, acc[m], 0, 0, 0);
      }
    }
    // bias (scale-folded) + packed store: Qb[b][t][oc]
    const int t = tb * 64 + tl;
#pragma unroll
    for (int m = 0; m < 2; ++m) {
      int oc0 = m * 16 + l4 * 4;
      u32 p0 = cvt_pk_bf16(acc[m][0] + bq[oc0] * QSCALE, acc[m][1] + bq[oc0 + 1] * QSCALE);
      u32 p1 = cvt_pk_bf16(acc[m][2] + bq[oc0 + 2] * QSCALE, acc[m][3] + bq[oc0 + 3] * QSCALE);
      u16* dst = Qb + ((size_t)b * 16384 + t) * 32 + oc0;
      *reinterpret_cast<u32*>(dst) = p0;
      *reinterpret_cast<u32*>(dst + 2) = p1;
    }
  } else {
    // ================= fused K+V path (round-3 verified) =================
    u16* xs = smem;  // pooled [64 s][256 c] bf16, swizzled
    const int b = bi >> 6, sy = bi & 63;
    const float* xb = x + (size_t)b * 256 * 16384;

    // pooled stage: xs[s][c] = mean2x2
#pragma unroll
    for (int rr = 0; rr < 4; ++rr) {
      int c = rr * 64 + (tid >> 2);
      int f4base = (tid & 3) * 8;
      const float* r0 = xb + (size_t)c * 16384 + (size_t)sy * 256;
#pragma unroll
      for (int u = 0; u < 8; ++u) {
        int jj = f4base + u;
        float4 a = *reinterpret_cast<const float4*>(r0 + jj * 4);
        float4 d = *reinterpret_cast<const float4*>(r0 + 128 + jj * 4);
        float p0 = (a.x + a.y + d.x + d.y) * 0.25f;
        float p1 = (a.z + a.w + d.z + d.w) * 0.25f;
        int s0 = jj * 2;
        *reinterpret_cast<u16*>((char*)xs + (s0 + 0) * 512 + (((c >> 3) ^ ((s0 + 0) & 7)) * 16) + (c & 7) * 2) = f2bf(p0);
        *reinterpret_cast<u16*>((char*)xs + (s0 + 1) * 512 + (((c >> 3) ^ ((s0 + 1) & 7)) * 16) + (c & 7) * 2) = f2bf(p1);
      }
    }
    __syncthreads();

    // GEMM: wave w = n-tile (16 s). m-tiles: 0..1 = K (32 oc), 2..17 = V (256 oc)
    f32x4 acc[18];
#pragma unroll
    for (int m = 0; m < 18; ++m) acc[m] = zero;
    const int sl = w * 16 + l15;  // local s (B col)
#pragma unroll
    for (int k = 0; k < 8; ++k) {
      bf16x8 bf = *reinterpret_cast<const bf16x8*>((char*)xs + sl * 512 +
                                                   (((k * 4 + l4) ^ (sl & 7)) * 16));
#pragma unroll
      for (int m = 0; m < 2; ++m) {
        const float* wr = Wk + (size_t)(m * 16 + l15) * 256 + k * 32 + l4 * 8;
        float4 fa = *reinterpret_cast<const float4*>(wr);
        float4 fb = *reinterpret_cast<const float4*>(wr + 4);
        acc[m] = __builtin_amdgcn_mfma_f32_16x16x32_bf16(f32x8_to_bf16x8(fa, fb), bf, acc[m], 0, 0, 0);
      }
#pragma unroll
      for (int m = 0; m < 16; ++m) {
        const float* wr = Wv + (size_t)(m * 16 + l15) * 256 + k * 32 + l4 * 8;
        float4 fa = *reinterpret_cast<const float4*>(wr);
        float4 fb = *reinterpret_cast<const float4*>(wr + 4);
        acc[2 + m] = __builtin_amdgcn_mfma_f32_16x16x32_bf16(f32x8_to_bf16x8(fa, fb), bf, acc[2 + m], 0, 0, 0);
      }
    }
    // K store (packed): Kt[b][s][oc]
#pragma unroll
    for (int m = 0; m < 2; ++m) {
      int oc0 = m * 16 + l4 * 4;
      u32 p0 = cvt_pk_bf16(acc[m][0] + bk[oc0], acc[m][1] + bk[oc0 + 1]);
      u32 p1 = cvt_pk_bf16(acc[m][2] + bk[oc0 + 2], acc[m][3] + bk[oc0 + 3]);
      u16* dst = Kt + ((size_t)b * 4096 + sy * 64 + sl) * 32 + oc0;
      *reinterpret_cast<u32*>(dst) = p0;
      *reinterpret_cast<u32*>(dst + 2) = p1;
    }
    // V store: Vb[b][oc][s]
#pragma unroll
    for (int m = 0; m < 16; ++m) {
#pragma unroll
      for (int r = 0; r < 4; ++r) {
        int oc = m * 16 + l4 * 4 + r;
        Vb[((size_t)b * 256 + oc) * 4096 + sy * 64 + sl] = f2bf(acc[2 + m][r] + bv[oc]);
      }
    }
  }
}

// ---------------------------------------------------------------------------
// attn v5: channel-split blocks for occupancy (v4 structure) + logit clamp
// (fminf(s,28) — no-op on correct path, makes inf/NaN impossible).
// Block = 64 tokens x 128 channels; QK+softmax duplicated across the two
// half-blocks, PV halves. 1024 blocks = 4/CU = 4 waves/SIMD. Swapped QK +
// packed softmax + double-buffered p_lds + 1 barrier/iter.
// ---------------------------------------------------------------------------
__global__ __launch_bounds__(256, 4) void attn_kernel(
    const u16* __restrict__ Qb, const u16* __restrict__ Kt, const u16* __restrict__ Vb,
    const float* __restrict__ x, const float* __restrict__ gamma, float* __restrict__ out) {
  __shared__ __align__(16) u16 p_lds[2][64 * 64];  // 16KB
  __shared__ float lred[4][64];

  const int tid = threadIdx.x;
  const int lane = tid & 63, w = tid >> 6;
  const int l15 = lane & 15, l4 = lane >> 4;
  const int raw = blockIdx.x;               // 0..1023
  const int xcd = raw & 7, loc = raw >> 3;  // loc 0..127
  const int b = xcd >> 2;
  const int h = loc & 1;
  const int t0 = ((xcd & 3) * 64 + (loc >> 1)) * 64;
  const int ch_base = h * 128 + w * 32;

  const u16* Qp = Qb + (size_t)(b * 16384 + t0) * 32;
  const u16* Kp = Kt + (size_t)b * 4096 * 32;
  const u16* Vp = Vb + (size_t)b * 256 * 4096;

  // Q fragments (loop-invariant): B-operand col = tok = mt*16+l15, k-chunk l4
  bf16x8 qfr[4];
#pragma unroll
  for (int mt = 0; mt < 4; ++mt)
    qfr[mt] = *reinterpret_cast<const bf16x8*>(Qp + (size_t)(mt * 16 + l15) * 32 + l4 * 8);

  const int key = w * 16 + l15;  // A-operand row for QK
  // P write address pieces: byte = tok*128 + (chunk^(tok&7))*16 + off
  const int pw_chunk = w * 2 + (l4 >> 1), pw_off = (l4 & 1) * 8;

  bf16x8 kfr = *reinterpret_cast<const bf16x8*>(Kp + (size_t)key * 32 + l4 * 8);
  bf16x8 vfr[2][2];
#pragma unroll
  for (int ks = 0; ks < 2; ++ks)
#pragma unroll
    for (int nt = 0; nt < 2; ++nt) {
      int ch = ch_base + nt * 16 + l15;
      vfr[ks][nt] = *reinterpret_cast<const bf16x8*>(Vp + (size_t)ch * 4096 + ks * 32 + l4 * 8);
    }

  f32x4 acc[4][2] = {};
  float lsum[4] = {};
  const f32x4 zero = {0.f, 0.f, 0.f, 0.f};

  // ---- prologue: QK(0) + exp + write p[0] ----
  {
    f32x4 sfr[4];
#pragma unroll
    for (int mt = 0; mt < 4; ++mt)
      sfr[mt] = __builtin_amdgcn_mfma_f32_16x16x32_bf16(kfr, qfr[mt], zero, 0, 0, 0);
    kfr = *reinterpret_cast<const bf16x8*>(Kp + (size_t)(64 + key) * 32 + l4 * 8);  // K(1)
#pragma unroll
    for (int mt = 0; mt < 4; ++mt) {
      float p0 = exp2_hw(fminf(sfr[mt][0], 28.f)), p1 = exp2_hw(fminf(sfr[mt][1], 28.f));
      float p2 = exp2_hw(fminf(sfr[mt][2], 28.f)), p3 = exp2_hw(fminf(sfr[mt][3], 28.f));
      lsum[mt] += (p0 + p1) + (p2 + p3);
      int tok = mt * 16 + l15;
      char* base = (char*)p_lds + tok * 128 + ((pw_chunk ^ (tok & 7)) * 16) + pw_off;
      *reinterpret_cast<u32*>(base) = cvt_pk_bf16(p0, p1);
      *reinterpret_cast<u32*>(base + 4) = cvt_pk_bf16(p2, p3);
    }
  }
  __syncthreads();

  for (int kt = 0; kt < 64; ++kt) {
    const int cur = kt & 1;
    // ---- PV(kt): acc += P * V^T ----
#pragma unroll
    for (int ks = 0; ks < 2; ++ks) {
      bf16x8 afr[4];
#pragma unroll
      for (int mt = 0; mt < 4; ++mt) {
        int tok = mt * 16 + l15;
        afr[mt] = *reinterpret_cast<const bf16x8*>((char*)p_lds + cur * 8192 + tok * 128 +
                                                   (((ks * 4 + l4) ^ (tok & 7)) * 16));
      }
#pragma unroll
      for (int mt = 0; mt < 4; ++mt)
#pragma unroll
        for (int nt = 0; nt < 2; ++nt)
          acc[mt][nt] =
              __builtin_amdgcn_mfma_f32_16x16x32_bf16(afr[mt], vfr[ks][nt], acc[mt][nt], 0, 0, 0);
    }
    if (kt < 63) {
      const int ktn = kt + 1;
      // prefetch V(kt+1) (vfr consumed above)
#pragma unroll
      for (int ks = 0; ks < 2; ++ks)
#pragma unroll
        for (int nt = 0; nt < 2; ++nt) {
          int ch = ch_base + nt * 16 + l15;
          vfr[ks][nt] = *reinterpret_cast<const bf16x8*>(Vp + (size_t)ch * 4096 + ktn * 64 +
                                                         ks * 32 + l4 * 8);
        }
      // ---- QK(kt+1) + exp + packed write p[cur^1] ----
      f32x4 sfr[4];
#pragma unroll
      for (int mt = 0; mt < 4; ++mt)
        sfr[mt] = __builtin_amdgcn_mfma_f32_16x16x32_bf16(kfr, qfr[mt], zero, 0, 0, 0);
      const int kt2 = (kt < 62) ? kt + 2 : 63;
      kfr = *reinterpret_cast<const bf16x8*>(Kp + (size_t)(kt2 * 64 + key) * 32 + l4 * 8);
#pragma unroll
      for (int mt = 0; mt < 4; ++mt) {
        float p0 = exp2_hw(fminf(sfr[mt][0], 28.f)), p1 = exp2_hw(fminf(sfr[mt][1], 28.f));
        float p2 = exp2_hw(fminf(sfr[mt][2], 28.f)), p3 = exp2_hw(fminf(sfr[mt][3], 28.f));
        lsum[mt] += (p0 + p1) + (p2 + p3);
        int tok = mt * 16 + l15;
        char* base =
            (char*)p_lds + (cur ^ 1) * 8192 + tok * 128 + ((pw_chunk ^ (tok & 7)) * 16) + pw_off;
        *reinterpret_cast<u32*>(base) = cvt_pk_bf16(p0, p1);
        *reinterpret_cast<u32*>(base + 4) = cvt_pk_bf16(p2, p3);
      }
    }
    __syncthreads();
  }

  // ---- row sums: reduce over l4 groups, then waves ----
#pragma unroll
  for (int i = 0; i < 4; ++i) {
    lsum[i] += __shfl_xor(lsum[i], 16, 64);
    lsum[i] += __shfl_xor(lsum[i], 32, 64);
  }
  if (l4 == 0) {
#pragma unroll
    for (int mt = 0; mt < 4; ++mt) lred[w][mt * 16 + l15] = lsum[mt];
  }
  __syncthreads();

  const float g = gamma[0];
  float linv[16];
#pragma unroll
  for (int mt = 0; mt < 4; ++mt)
#pragma unroll
    for (int r = 0; r < 4; ++r) {
      int tok = mt * 16 + l4 * 4 + r;
      linv[mt * 4 + r] = 1.0f / (lred[0][tok] + lred[1][tok] + lred[2][tok] + lred[3][tok]);
    }
  // ---- epilogue: out = gamma * acc / l + x ----
#pragma unroll
  for (int mt = 0; mt < 4; ++mt) {
#pragma unroll
    for (int nt = 0; nt < 2; ++nt) {
      int ch = ch_base + nt * 16 + l15;
      size_t idx = ((size_t)(b * 256 + ch)) * 16384 + t0 + mt * 16 + l4 * 4;
      float4 xr = *reinterpret_cast<const float4*>(x + idx);
      float4 o;
      o.x = g * acc[mt][nt][0] * linv[mt * 4 + 0] + xr.x;
      o.y = g * acc[mt][nt][1] * linv[mt * 4 + 1] + xr.y;
      o.z = g * acc[mt][nt][2] * linv[mt * 4 + 2] + xr.z;
      o.w = g * acc[mt][nt][3] * linv[mt * 4 + 3] + xr.w;
      *reinterpret_cast<float4*>(out + idx) = o;
    }
  }
}

// ---------------------------------------------------------------------------
extern "C" void kernel_launch(void* const* d_in, const int* in_sizes, int n_in,
                              void* d_out, int out_size, void* d_ws, size_t ws_size,
                              hipStream_t stream) {
  const float* x = (const float*)d_in[0];
  const float* Wq = (const float*)d_in[1];
  const float* bq = (const float*)d_in[2];
  const float* Wk = (const float*)d_in[3];
  const float* bk = (const float*)d_in[4];
  const float* Wv = (const float*)d_in[5];
  const float* bv = (const float*)d_in[6];
  const float* gamma = (const float*)d_in[7];
  float* out = (float*)d_out;

  char* ws = (char*)d_ws;
  u16* Qb = (u16*)ws;                                // 2 MB  : [2][16384][32]
  u16* Kt = (u16*)(ws + (2u << 20));                 // 512 KB: [2][4096][32]
  u16* Vb = (u16*)(ws + (2u << 20) + (512u << 10));  // 4 MB  : [2][256][4096]

  proj_kernel<<<dim3(640), 256, 0, stream>>>(x, Wq, bq, Wk, bk, Wv, bv, Qb, Kt, Vb);
  attn_kernel<<<dim3(1024), 256, 0, stream>>>(Qb, Kt, Vb, x, gamma, out);
}